// Round 8
// baseline (77.494 us; speedup 1.0000x reference)
//
#include <hip/hip_runtime.h>
#include <stdint.h>

// MoEDense: y[b,f] = x[b,:] @ K[t[b]] + bias[t[b]]
// B=8192, D=F=128, T=64, fp32 in/out, int32 idx. Threshold 0.103 abs.
//
// R8: BISECT of R7's 3-way bundle (R7 failed absmax 3.67, cause not found
// by inspection). This round = R6 (validated 0.03125) + two of the three:
//   S: coalesced tidx scan (thread reads tp[c*256+tid]; canonical rank
//      order becomes (wave,lane,c,j)-major -- benign permutation, every
//      block derives identical ranks from identical data).
//   A: prep kernel converts x -> bf16 in ws once; A-fragments are single
//      16B contiguous global loads; A-LDS staging phase + barrier deleted.
//   B: REVERTED to R6's exact in-register f2bf(kern) path (validated).
// If R8 passes -> R7's bug is in the Kt transpose path; if fails -> S/A.
// Expected chain ~20us -> ~16us (scan TA -3.4, A staging -2, +prep +gap).

#define D_ 128
#define F_ 128
#define T_ 64
#define TILE_M 32
#define TPE 16

typedef __attribute__((ext_vector_type(8))) short short8;
typedef __attribute__((ext_vector_type(8))) unsigned short ushort8;
typedef __attribute__((ext_vector_type(4))) float floatx4;

__device__ __forceinline__ int clamp_t(int t) {
    return t < 0 ? 0 : (t > T_ - 1 ? T_ - 1 : t);
}
__device__ __forceinline__ unsigned short f2bf(float f) {  // RNE fp32->bf16
    union { float f; unsigned u; } c; c.f = f;
    unsigned r = c.u + 0x7fffu + ((c.u >> 16) & 1u);
    return (unsigned short)(r >> 16);
}

// x fp32 -> bf16 into ws (offset 0): 512 blocks x 256 thr x 8 elements.
__global__ __launch_bounds__(256) void moe_prep(
    const float* __restrict__ x, unsigned short* __restrict__ ws)
{
    const int i0 = (blockIdx.x * 256 + threadIdx.x) * 8;
    const float4* xp = reinterpret_cast<const float4*>(x + i0);
    const float4 a = xp[0], b = xp[1];
    ushort8 h;
    h[0]=f2bf(a.x); h[1]=f2bf(a.y); h[2]=f2bf(a.z); h[3]=f2bf(a.w);
    h[4]=f2bf(b.x); h[5]=f2bf(b.y); h[6]=f2bf(b.z); h[7]=f2bf(b.w);
    *reinterpret_cast<ushort8*>(&ws[i0]) = h;
}

__global__ __launch_bounds__(256) void moe_fused(
    const int* __restrict__ tidx,            // [8192]
    const unsigned short* __restrict__ ws,   // x_bf16 [8192][128]
    const float* __restrict__ kern,          // [64][128][128] fp32
    const float* __restrict__ bias,          // [64][128]
    float* __restrict__ out)                 // [8192][128]
{
    const int e    = blockIdx.x >> 4;
    const int tb   = blockIdx.x & (TPE - 1);
    const int m0   = tb * TILE_M;
    const int tid  = threadIdx.x;
    const int wv   = tid >> 6;
    const int lane = tid & 63;

    __shared__ int wtot[4];
    __shared__ int slot[TILE_M];

    // ---- S: coalesced binning, thread owns rows (c*256+tid)*4 + j ----
    const int4* tp = reinterpret_cast<const int4*>(tidx);
    int4 v[8];
    #pragma unroll
    for (int c = 0; c < 8; ++c) v[c] = tp[c * 256 + tid];

    int my = 0;
    #pragma unroll
    for (int c = 0; c < 8; ++c) {
        my += (clamp_t(v[c].x) == e);
        my += (clamp_t(v[c].y) == e);
        my += (clamp_t(v[c].z) == e);
        my += (clamp_t(v[c].w) == e);
    }
    int pre = my;                            // wave inclusive prefix
    #pragma unroll
    for (int d = 1; d < 64; d <<= 1) {
        int u = __shfl_up(pre, d);
        if (lane >= d) pre += u;
    }
    if (lane == 63) wtot[wv] = pre;
    __syncthreads();
    int wbase = 0, cnt = 0;
    #pragma unroll
    for (int w = 0; w < 4; ++w) {
        const int t = wtot[w];
        if (w < wv) wbase += t;
        cnt += t;
    }
    if (m0 >= cnt) return;                   // uniform exit (empty tile)
    const int base = wbase + pre - my;       // exclusive global rank

    if (base < m0 + TILE_M && base + my > m0) {
        int run = base;
        #pragma unroll
        for (int c = 0; c < 8; ++c) {
            const int row4 = (c * 256 + tid) * 4;
            const int tt[4] = { v[c].x, v[c].y, v[c].z, v[c].w };
            #pragma unroll
            for (int j = 0; j < 4; ++j) {
                if (clamp_t(tt[j]) == e) {
                    if (run >= m0 && run < m0 + TILE_M)
                        slot[run - m0] = row4 + j;
                    ++run;
                }
            }
        }
    }
    __syncthreads();

    // ---- main loop: A frags from global bf16 (A); B in-reg cvt (R6) ----
    const int quad = lane >> 4;
    const int l16  = lane & 15;
    const int n0w  = wv * 32;

    const int rA = (m0 + l16 < cnt)      ? slot[l16]      : 0;  // masked later
    const int rB = (m0 + 16 + l16 < cnt) ? slot[16 + l16] : 0;

    floatx4 acc00 = {0.f,0.f,0.f,0.f}, acc01 = acc00, acc10 = acc00, acc11 = acc00;
    const float* Bp = kern + e * (D_ * F_);

    #pragma unroll
    for (int kc = 0; kc < 4; ++kc) {
        const int k0 = kc * 32;
        // A frags: lane holds x_bf16[r][k0 + quad*8 + j]
        const short8 a0 = *reinterpret_cast<const short8*>(&ws[rA * D_ + k0 + quad * 8]);
        const short8 a1 = *reinterpret_cast<const short8*>(&ws[rB * D_ + k0 + quad * 8]);
        // B frags (R6-validated): lane holds K[k0+quad*8+j][n0w(+16) + l16]
        const float* bp = Bp + (k0 + quad * 8) * F_ + n0w + l16;
        short8 b0, b1;
        #pragma unroll
        for (int j = 0; j < 8; ++j) {
            b0[j] = (short)f2bf(bp[j * F_]);
            b1[j] = (short)f2bf(bp[j * F_ + 16]);
        }
        acc00 = __builtin_amdgcn_mfma_f32_16x16x32_bf16(a0, b0, acc00, 0, 0, 0);
        acc01 = __builtin_amdgcn_mfma_f32_16x16x32_bf16(a0, b1, acc01, 0, 0, 0);
        acc10 = __builtin_amdgcn_mfma_f32_16x16x32_bf16(a1, b0, acc10, 0, 0, 0);
        acc11 = __builtin_amdgcn_mfma_f32_16x16x32_bf16(a1, b1, acc11, 0, 0, 0);
    }

    // ---- epilogue: C row m = msub*16 + quad*4 + reg, col n0w + l16 (+16) ----
    const float bs0 = bias[e * F_ + n0w + l16];
    const float bs1 = bias[e * F_ + n0w + l16 + 16];
    #pragma unroll
    for (int reg = 0; reg < 4; ++reg) {
        const int mA = quad * 4 + reg;
        if (m0 + mA < cnt) {
            const int r = slot[mA];
            out[r * F_ + n0w + l16]      = acc00[reg] + bs0;
            out[r * F_ + n0w + l16 + 16] = acc01[reg] + bs1;
        }
        const int mB = 16 + mA;
        if (m0 + mB < cnt) {
            const int r = slot[mB];
            out[r * F_ + n0w + l16]      = acc10[reg] + bs0;
            out[r * F_ + n0w + l16 + 16] = acc11[reg] + bs1;
        }
    }
}

extern "C" void kernel_launch(void* const* d_in, const int* in_sizes, int n_in,
                              void* d_out, int out_size, void* d_ws, size_t ws_size,
                              hipStream_t stream) {
    const float* x    = (const float*)d_in[0];
    const int*   tidx = (const int*)d_in[1];
    const float* kern = (const float*)d_in[2];
    const float* bias = (const float*)d_in[3];
    float* out = (float*)d_out;
    unsigned short* wsu = (unsigned short*)d_ws;
    (void)in_sizes; (void)n_in; (void)out_size; (void)ws_size;

    // B = 8192 fixed by the problem (binning layout: 8 chunks x 256 thr x 4).
    moe_prep <<<512,  256, 0, stream>>>(x, wsu);
    moe_fused<<<T_ * TPE, 256, 0, stream>>>(tidx, wsu, kern, bias, out);
}